// Round 2
// baseline (469.499 us; speedup 1.0000x reference)
//
#include <hip/hip_runtime.h>
#include <stdint.h>

typedef __bf16 bf16_t;
typedef float f32x4 __attribute__((ext_vector_type(4)));
typedef __bf16 bf16x8 __attribute__((ext_vector_type(8)));

#define D_ 1024
#define M_ 8192

__device__ __forceinline__ f32x4 mfma16(bf16x8 a, bf16x8 b, f32x4 c) {
  return __builtin_amdgcn_mfma_f32_16x16x32_bf16(a, b, c, 0, 0, 0);
}

__device__ __forceinline__ void gl_lds16(const bf16_t* g, bf16_t* l) {
  __builtin_amdgcn_global_load_lds(
      (const __attribute__((address_space(1))) unsigned int*)g,
      (__attribute__((address_space(3))) unsigned int*)l, 16, 0, 0);
}

// ---------------- fp32 -> bf16 convert (8 elems/thread) ----------------
__global__ __launch_bounds__(256) void cvt_bf16(const float* __restrict__ in,
                                                bf16_t* __restrict__ out, int n8) {
  int i = blockIdx.x * 256 + threadIdx.x;
  if (i >= n8) return;
  const f32x4* p = (const f32x4*)(in + (size_t)i * 8);
  f32x4 a = p[0], b = p[1];
  bf16x8 o;
  o[0] = (bf16_t)a.x; o[1] = (bf16_t)a.y; o[2] = (bf16_t)a.z; o[3] = (bf16_t)a.w;
  o[4] = (bf16_t)b.x; o[5] = (bf16_t)b.y; o[6] = (bf16_t)b.z; o[7] = (bf16_t)b.w;
  *(bf16x8*)(out + (size_t)i * 8) = o;
}

// 4 weight matrices in one launch (each 1024x1024 = 131072 groups of 8)
__global__ __launch_bounds__(256) void cvt_w4(
    const float* __restrict__ s0, const float* __restrict__ s1,
    const float* __restrict__ s2, const float* __restrict__ s3,
    bf16_t* __restrict__ d0, bf16_t* __restrict__ d1,
    bf16_t* __restrict__ d2, bf16_t* __restrict__ d3) {
  int gid = blockIdx.x;
  int which = gid >> 9;
  const float* s = which == 0 ? s0 : which == 1 ? s1 : which == 2 ? s2 : s3;
  bf16_t* d = which == 0 ? d0 : which == 1 ? d1 : which == 2 ? d2 : d3;
  int i = (gid & 511) * 256 + threadIdx.x;
  const f32x4* p = (const f32x4*)(s + (size_t)i * 8);
  f32x4 a = p[0], b = p[1];
  bf16x8 o;
  o[0] = (bf16_t)a.x; o[1] = (bf16_t)a.y; o[2] = (bf16_t)a.z; o[3] = (bf16_t)a.w;
  o[4] = (bf16_t)b.x; o[5] = (bf16_t)b.y; o[6] = (bf16_t)b.z; o[7] = (bf16_t)b.w;
  *(bf16x8*)(d + (size_t)i * 8) = o;
}

// ---------------- shared 128x128x(K=1024) bf16 GEMM core (C = A @ W^T) ----------------
__device__ __forceinline__ void gemm_core(const bf16_t* __restrict__ A,
                                          const bf16_t* __restrict__ W,
                                          int m0, int n0,
                                          bf16_t* As, bf16_t* Bs,
                                          f32x4 acc[4][4]) {
  const int t = threadIdx.x;
  const int l = t & 63, w = t >> 6;
  const int wr = w >> 1, wc = w & 1;
  const int lr = l & 15, lg = l >> 4;
  const int srow = t >> 2;
  const int scol = (t & 3) * 8;
  const bf16_t* gA0 = A + (size_t)(m0 + srow) * D_ + scol;
  const bf16_t* gA1 = A + (size_t)(m0 + 64 + srow) * D_ + scol;
  const bf16_t* gB0 = W + (size_t)(n0 + srow) * D_ + scol;
  const bf16_t* gB1 = W + (size_t)(n0 + 64 + srow) * D_ + scol;

  for (int k0 = 0; k0 < D_; k0 += 32) {
    gl_lds16(gA0 + k0, As + t * 8);
    gl_lds16(gA1 + k0, As + 2048 + t * 8);
    gl_lds16(gB0 + k0, Bs + t * 8);
    gl_lds16(gB1 + k0, Bs + 2048 + t * 8);
    __syncthreads();
    bf16x8 af[4], bfr[4];
#pragma unroll
    for (int i = 0; i < 4; ++i)
      af[i] = *(const bf16x8*)(As + (wr * 64 + i * 16 + lr) * 32 + lg * 8);
#pragma unroll
    for (int i = 0; i < 4; ++i)
      bfr[i] = *(const bf16x8*)(Bs + (wc * 64 + i * 16 + lr) * 32 + lg * 8);
#pragma unroll
    for (int mi = 0; mi < 4; ++mi)
#pragma unroll
      for (int ni = 0; ni < 4; ++ni)
        acc[mi][ni] = mfma16(af[mi], bfr[ni], acc[mi][ni]);
    __syncthreads();
  }
}

// ---------------- QKV GEMM: z selects (W, bias, out); out bf16 ----------------
__global__ __launch_bounds__(256) void gemm_qkv(
    const bf16_t* __restrict__ A,
    const bf16_t* __restrict__ Wq, const bf16_t* __restrict__ Wk, const bf16_t* __restrict__ Wv,
    const float* __restrict__ bq, const float* __restrict__ bk, const float* __restrict__ bv,
    bf16_t* __restrict__ Oq, bf16_t* __restrict__ Ok, bf16_t* __restrict__ Ov) {
  __shared__ bf16_t As[128 * 32], Bs[128 * 32];
  int z = blockIdx.z;
  const bf16_t* W = z == 0 ? Wq : (z == 1 ? Wk : Wv);
  const float* bias = z == 0 ? bq : (z == 1 ? bk : bv);
  bf16_t* O = z == 0 ? Oq : (z == 1 ? Ok : Ov);
  int m0 = blockIdx.y * 128, n0 = blockIdx.x * 128;
  f32x4 acc[4][4] = {};
  gemm_core(A, W, m0, n0, As, Bs, acc);
  int t = threadIdx.x, l = t & 63, w = t >> 6;
  int wr = w >> 1, wc = w & 1, lr = l & 15, lg = l >> 4;
#pragma unroll
  for (int mi = 0; mi < 4; ++mi) {
#pragma unroll
    for (int ni = 0; ni < 4; ++ni) {
      int col = n0 + wc * 64 + ni * 16 + lr;
      float bb = bias[col];
      int row = m0 + wr * 64 + mi * 16 + lg * 4;
      bf16_t* op = O + (size_t)row * D_ + col;
#pragma unroll
      for (int r = 0; r < 4; ++r)
        op[(size_t)r * D_] = (bf16_t)(acc[mi][ni][r] + bb);
    }
  }
}

// ---------------- proj GEMM: out fp32 = acc + bo + x (residual) ----------------
__global__ __launch_bounds__(256) void gemm_proj(
    const bf16_t* __restrict__ A, const bf16_t* __restrict__ W,
    const float* __restrict__ bias, const float* __restrict__ xres,
    float* __restrict__ O) {
  __shared__ bf16_t As[128 * 32], Bs[128 * 32];
  int m0 = blockIdx.y * 128, n0 = blockIdx.x * 128;
  f32x4 acc[4][4] = {};
  gemm_core(A, W, m0, n0, As, Bs, acc);
  int t = threadIdx.x, l = t & 63, w = t >> 6;
  int wr = w >> 1, wc = w & 1, lr = l & 15, lg = l >> 4;
#pragma unroll
  for (int mi = 0; mi < 4; ++mi) {
#pragma unroll
    for (int ni = 0; ni < 4; ++ni) {
      int col = n0 + wc * 64 + ni * 16 + lr;
      float bb = bias[col];
      int row = m0 + wr * 64 + mi * 16 + lg * 4;
#pragma unroll
      for (int r = 0; r < 4; ++r) {
        size_t idx = (size_t)(row + r) * D_ + col;
        O[idx] = acc[mi][ni][r] + bb + xres[idx];
      }
    }
  }
}

// ---------------- V transpose: [128][1024][64] -> [128][64][1024] ----------------
__global__ __launch_bounds__(256) void transpose_v(const bf16_t* __restrict__ V,
                                                   bf16_t* __restrict__ Vt) {
  int gid = blockIdx.x * 256 + threadIdx.x;
  int s8 = gid & 127;
  int dh = (gid >> 7) & 63;
  int bh = gid >> 13;
  const bf16_t* src = V + (size_t)bh * 65536 + (size_t)(s8 * 8) * 64 + dh;
  bf16x8 v;
#pragma unroll
  for (int j = 0; j < 8; ++j) v[j] = src[(size_t)j * 64];
  *(bf16x8*)(Vt + (size_t)bh * 65536 + (size_t)dh * 1024 + s8 * 8) = v;
}

// ---------------- fused attention per (bh, 32-row q tile) ----------------
// Scores held in REGISTERS (64 f32/lane). LDS holds only bf16 exp(S) for PV.
__global__ __launch_bounds__(512, 4) void attn_kernel(
    const bf16_t* __restrict__ Q, const bf16_t* __restrict__ K,
    const bf16_t* __restrict__ Vt, float* __restrict__ alpha,
    bf16_t* __restrict__ ctx) {
  __shared__ bf16_t sP[32][1032];   // 66 KB: exp(S) in bf16, PV A-operand
  __shared__ float sRS[8][32];      // per-wave row sums
  __shared__ float sL[32];          // 1/rowsum

  int id = blockIdx.x;
  // XCD-friendly: same XCD sweeps 32 consecutive q-tiles of one head
  int g = id >> 3, x = id & 7;
  int qt = g & 31;
  int bh = ((g >> 5) << 3) | x;
  int q0 = qt * 32;

  const bf16_t* Qb = Q + (size_t)bh * 65536;
  const bf16_t* Kb = K + (size_t)bh * 65536;
  const bf16_t* Vb = Vt + (size_t)bh * 65536;
  float* Ab = alpha + (size_t)bh * 1048576 + (size_t)q0 * 1024;

  int t = threadIdx.x, l = t & 63, w = t >> 6;
  int lr = l & 15, lg = l >> 4;

  // ---- Q fragments (rows q0+mi*16+lr, k-groups kk*32+lg*8) ----
  bf16x8 qa[2][2];
#pragma unroll
  for (int mi = 0; mi < 2; ++mi)
#pragma unroll
    for (int kk = 0; kk < 2; ++kk)
      qa[mi][kk] = *(const bf16x8*)(Qb + (size_t)(q0 + mi * 16 + lr) * 64 + kk * 32 + lg * 8);

  // ---- Phase A: scores -> exp, all in registers ----
  f32x4 ex[8][2];
  f32x4 pa0 = {0.f, 0.f, 0.f, 0.f}, pa1 = {0.f, 0.f, 0.f, 0.f};
#pragma unroll
  for (int tt = 0; tt < 8; ++tt) {
    int n0 = w * 128 + tt * 16;
    bf16x8 kb0 = *(const bf16x8*)(Kb + (size_t)(n0 + lr) * 64 + lg * 8);
    bf16x8 kb1 = *(const bf16x8*)(Kb + (size_t)(n0 + lr) * 64 + 32 + lg * 8);
    f32x4 a0 = {0.f, 0.f, 0.f, 0.f};
    f32x4 a1 = {0.f, 0.f, 0.f, 0.f};
    a0 = mfma16(qa[0][0], kb0, a0);
    a0 = mfma16(qa[0][1], kb1, a0);
    a1 = mfma16(qa[1][0], kb0, a1);
    a1 = mfma16(qa[1][1], kb1, a1);
#pragma unroll
    for (int r = 0; r < 4; ++r) {
      float e0 = __expf(a0[r] * 0.125f);
      float e1 = __expf(a1[r] * 0.125f);
      ex[tt][0][r] = e0; pa0[r] += e0;
      ex[tt][1][r] = e1; pa1[r] += e1;
    }
  }
  // reduce across the 16 lanes of each lg-group (sums this wave's 128 cols)
#pragma unroll
  for (int off = 1; off <= 8; off <<= 1) {
#pragma unroll
    for (int r = 0; r < 4; ++r) {
      pa0[r] += __shfl_xor(pa0[r], off);
      pa1[r] += __shfl_xor(pa1[r], off);
    }
  }
  if (lr == 0) {
#pragma unroll
    for (int r = 0; r < 4; ++r) {
      sRS[w][lg * 4 + r] = pa0[r];
      sRS[w][16 + lg * 4 + r] = pa1[r];
    }
  }
  __syncthreads();
  if (t < 32) {
    float s = 0.f;
#pragma unroll
    for (int ww = 0; ww < 8; ++ww) s += sRS[ww][t];
    sL[t] = 1.0f / s;
  }
  __syncthreads();

  // ---- Phase B: write alpha (fp32, normalized, from regs) + sP (bf16 exp) ----
  float inv0[4], inv1[4];
#pragma unroll
  for (int r = 0; r < 4; ++r) {
    inv0[r] = sL[lg * 4 + r];
    inv1[r] = sL[16 + lg * 4 + r];
  }
#pragma unroll
  for (int tt = 0; tt < 8; ++tt) {
    int col = w * 128 + tt * 16 + lr;
#pragma unroll
    for (int r = 0; r < 4; ++r) {
      int row0 = lg * 4 + r, row1 = 16 + lg * 4 + r;
      Ab[(size_t)row0 * 1024 + col] = ex[tt][0][r] * inv0[r];
      Ab[(size_t)row1 * 1024 + col] = ex[tt][1][r] * inv1[r];
      sP[row0][col] = (bf16_t)ex[tt][0][r];
      sP[row1][col] = (bf16_t)ex[tt][1][r];
    }
  }
  __syncthreads();

  // ---- Phase C: PV from sP (bf16) x Vt(global); wave tile 16q x 16dh ----
  {
    int wm = w >> 2, wn = w & 3;
    f32x4 acc = {0.f, 0.f, 0.f, 0.f};
    const bf16_t* vp = Vb + (size_t)(wn * 16 + lr) * 1024 + lg * 8;
    const bf16_t* pp = &sP[wm * 16 + lr][lg * 8];
#pragma unroll 8
    for (int n0 = 0; n0 < 1024; n0 += 32) {
      bf16x8 ea = *(const bf16x8*)(pp + n0);
      bf16x8 vb = *(const bf16x8*)(vp + n0);
      acc = mfma16(ea, vb, acc);
    }
    bf16_t* cp = ctx + (size_t)bh * 65536 + (size_t)(q0 + wm * 16 + lg * 4) * 64 + wn * 16 + lr;
#pragma unroll
    for (int r = 0; r < 4; ++r)
      cp[(size_t)r * 64] = (bf16_t)(acc[r] * sL[wm * 16 + lg * 4 + r]);
  }
}

// ---------------- LayerNorm in place on d_out rows ----------------
__global__ __launch_bounds__(256) void ln_kernel(float* __restrict__ io,
                                                 const float* __restrict__ gamma,
                                                 const float* __restrict__ beta) {
  int row = blockIdx.x;
  int t = threadIdx.x;
  float* p = io + (size_t)row * 1024;
  f32x4 v = *(const f32x4*)(p + t * 4);
  float s = v[0] + v[1] + v[2] + v[3];
  float s2 = v[0] * v[0] + v[1] * v[1] + v[2] * v[2] + v[3] * v[3];
#pragma unroll
  for (int off = 1; off <= 32; off <<= 1) {
    s += __shfl_xor(s, off);
    s2 += __shfl_xor(s2, off);
  }
  __shared__ float ps[4], ps2[4];
  int w = t >> 6, l = t & 63;
  if (l == 0) { ps[w] = s; ps2[w] = s2; }
  __syncthreads();
  float S = ps[0] + ps[1] + ps[2] + ps[3];
  float S2 = ps2[0] + ps2[1] + ps2[2] + ps2[3];
  float mu = S * (1.f / 1024.f);
  float var = S2 * (1.f / 1024.f) - mu * mu;
  float rs = rsqrtf(var + 1e-5f);
  f32x4 g = *(const f32x4*)(gamma + t * 4);
  f32x4 b = *(const f32x4*)(beta + t * 4);
  f32x4 o;
  o[0] = (v[0] - mu) * rs * g[0] + b[0];
  o[1] = (v[1] - mu) * rs * g[1] + b[1];
  o[2] = (v[2] - mu) * rs * g[2] + b[2];
  o[3] = (v[3] - mu) * rs * g[3] + b[3];
  *(f32x4*)(p + t * 4) = o;
}

extern "C" void kernel_launch(void* const* d_in, const int* in_sizes, int n_in,
                              void* d_out, int out_size, void* d_ws, size_t ws_size,
                              hipStream_t stream) {
  const float* x = (const float*)d_in[0];
  const float* Wq = (const float*)d_in[1];
  const float* bq = (const float*)d_in[2];
  const float* Wk = (const float*)d_in[3];
  const float* bk = (const float*)d_in[4];
  const float* Wv = (const float*)d_in[5];
  const float* bv = (const float*)d_in[6];
  const float* Wo = (const float*)d_in[7];
  const float* bo = (const float*)d_in[8];
  const float* gamma = (const float*)d_in[9];
  const float* beta = (const float*)d_in[10];

  char* ws = (char*)d_ws;
  size_t off = 0;
  bf16_t* xb = (bf16_t*)(ws + off);  off += (size_t)M_ * D_ * 2;
  bf16_t* Wqb = (bf16_t*)(ws + off); off += (size_t)D_ * D_ * 2;
  bf16_t* Wkb = (bf16_t*)(ws + off); off += (size_t)D_ * D_ * 2;
  bf16_t* Wvb = (bf16_t*)(ws + off); off += (size_t)D_ * D_ * 2;
  bf16_t* Wob = (bf16_t*)(ws + off); off += (size_t)D_ * D_ * 2;
  bf16_t* Qb = (bf16_t*)(ws + off);  off += (size_t)M_ * D_ * 2;
  bf16_t* Kb = (bf16_t*)(ws + off);  off += (size_t)M_ * D_ * 2;
  bf16_t* Vb = (bf16_t*)(ws + off);  off += (size_t)M_ * D_ * 2;
  bf16_t* Vtb = (bf16_t*)(ws + off); off += (size_t)M_ * D_ * 2;
  bf16_t* ctxb = (bf16_t*)(ws + off); off += (size_t)M_ * D_ * 2;

  float* out0 = (float*)d_out;
  float* alpha = out0 + (size_t)M_ * D_;

  cvt_bf16<<<4096, 256, 0, stream>>>(x, xb, 1048576);
  cvt_w4<<<2048, 256, 0, stream>>>(Wq, Wk, Wv, Wo, Wqb, Wkb, Wvb, Wob);

  gemm_qkv<<<dim3(8, 64, 3), 256, 0, stream>>>(xb, Wqb, Wkb, Wvb, bq, bk, bv, Qb, Kb, Vb);
  transpose_v<<<4096, 256, 0, stream>>>(Vb, Vtb);
  attn_kernel<<<4096, 512, 0, stream>>>(Qb, Kb, Vtb, alpha, ctxb);
  gemm_proj<<<dim3(8, 64), 256, 0, stream>>>(ctxb, Wob, bo, x, out0);
  ln_kernel<<<8192, 256, 0, stream>>>(out0, gamma, beta);
}

// Round 3
// 429.021 us; speedup vs baseline: 1.0944x; 1.0944x over previous
//
#include <hip/hip_runtime.h>
#include <stdint.h>

typedef __bf16 bf16_t;
typedef float f32x4 __attribute__((ext_vector_type(4)));
typedef __bf16 bf16x8 __attribute__((ext_vector_type(8)));
typedef __bf16 bf16x4 __attribute__((ext_vector_type(4)));

#define D_ 1024
#define M_ 8192

__device__ __forceinline__ f32x4 mfma16(bf16x8 a, bf16x8 b, f32x4 c) {
  return __builtin_amdgcn_mfma_f32_16x16x32_bf16(a, b, c, 0, 0, 0);
}

__device__ __forceinline__ void gl_lds16(const bf16_t* g, bf16_t* l) {
  __builtin_amdgcn_global_load_lds(
      (const __attribute__((address_space(1))) unsigned int*)g,
      (__attribute__((address_space(3))) unsigned int*)l, 16, 0, 0);
}

// ---------------- fp32 -> bf16 convert (8 elems/thread) ----------------
__global__ __launch_bounds__(256) void cvt_bf16(const float* __restrict__ in,
                                                bf16_t* __restrict__ out, int n8) {
  int i = blockIdx.x * 256 + threadIdx.x;
  if (i >= n8) return;
  const f32x4* p = (const f32x4*)(in + (size_t)i * 8);
  f32x4 a = p[0], b = p[1];
  bf16x8 o;
  o[0] = (bf16_t)a.x; o[1] = (bf16_t)a.y; o[2] = (bf16_t)a.z; o[3] = (bf16_t)a.w;
  o[4] = (bf16_t)b.x; o[5] = (bf16_t)b.y; o[6] = (bf16_t)b.z; o[7] = (bf16_t)b.w;
  *(bf16x8*)(out + (size_t)i * 8) = o;
}

// 4 weight matrices in one launch
__global__ __launch_bounds__(256) void cvt_w4(
    const float* __restrict__ s0, const float* __restrict__ s1,
    const float* __restrict__ s2, const float* __restrict__ s3,
    bf16_t* __restrict__ d0, bf16_t* __restrict__ d1,
    bf16_t* __restrict__ d2, bf16_t* __restrict__ d3) {
  int gid = blockIdx.x;
  int which = gid >> 9;
  const float* s = which == 0 ? s0 : which == 1 ? s1 : which == 2 ? s2 : s3;
  bf16_t* d = which == 0 ? d0 : which == 1 ? d1 : which == 2 ? d2 : d3;
  int i = (gid & 511) * 256 + threadIdx.x;
  const f32x4* p = (const f32x4*)(s + (size_t)i * 8);
  f32x4 a = p[0], b = p[1];
  bf16x8 o;
  o[0] = (bf16_t)a.x; o[1] = (bf16_t)a.y; o[2] = (bf16_t)a.z; o[3] = (bf16_t)a.w;
  o[4] = (bf16_t)b.x; o[5] = (bf16_t)b.y; o[6] = (bf16_t)b.z; o[7] = (bf16_t)b.w;
  *(bf16x8*)(d + (size_t)i * 8) = o;
}

// ---------------- shared 128x128x(K=1024) bf16 GEMM core (C = A @ W^T) ----------------
__device__ __forceinline__ void gemm_core(const bf16_t* __restrict__ A,
                                          const bf16_t* __restrict__ W,
                                          int m0, int n0,
                                          bf16_t* As, bf16_t* Bs,
                                          f32x4 acc[4][4]) {
  const int t = threadIdx.x;
  const int l = t & 63, w = t >> 6;
  const int wr = w >> 1, wc = w & 1;
  const int lr = l & 15, lg = l >> 4;
  const int srow = t >> 2;
  const int scol = (t & 3) * 8;
  const bf16_t* gA0 = A + (size_t)(m0 + srow) * D_ + scol;
  const bf16_t* gA1 = A + (size_t)(m0 + 64 + srow) * D_ + scol;
  const bf16_t* gB0 = W + (size_t)(n0 + srow) * D_ + scol;
  const bf16_t* gB1 = W + (size_t)(n0 + 64 + srow) * D_ + scol;

  for (int k0 = 0; k0 < D_; k0 += 32) {
    gl_lds16(gA0 + k0, As + t * 8);
    gl_lds16(gA1 + k0, As + 2048 + t * 8);
    gl_lds16(gB0 + k0, Bs + t * 8);
    gl_lds16(gB1 + k0, Bs + 2048 + t * 8);
    __syncthreads();
    bf16x8 af[4], bfr[4];
#pragma unroll
    for (int i = 0; i < 4; ++i)
      af[i] = *(const bf16x8*)(As + (wr * 64 + i * 16 + lr) * 32 + lg * 8);
#pragma unroll
    for (int i = 0; i < 4; ++i)
      bfr[i] = *(const bf16x8*)(Bs + (wc * 64 + i * 16 + lr) * 32 + lg * 8);
#pragma unroll
    for (int mi = 0; mi < 4; ++mi)
#pragma unroll
      for (int ni = 0; ni < 4; ++ni)
        acc[mi][ni] = mfma16(af[mi], bfr[ni], acc[mi][ni]);
    __syncthreads();
  }
}

// ---------------- QKV GEMM: z selects (W, bias, out); out bf16 ----------------
// z==0 (Q): output pre-scaled by 0.125 (= dh^-0.5), exact power of two.
__global__ __launch_bounds__(256) void gemm_qkv(
    const bf16_t* __restrict__ A,
    const bf16_t* __restrict__ Wq, const bf16_t* __restrict__ Wk, const bf16_t* __restrict__ Wv,
    const float* __restrict__ bq, const float* __restrict__ bk, const float* __restrict__ bv,
    bf16_t* __restrict__ Oq, bf16_t* __restrict__ Ok, bf16_t* __restrict__ Ov) {
  __shared__ bf16_t As[128 * 32], Bs[128 * 32];
  int z = blockIdx.z;
  const bf16_t* W = z == 0 ? Wq : (z == 1 ? Wk : Wv);
  const float* bias = z == 0 ? bq : (z == 1 ? bk : bv);
  bf16_t* O = z == 0 ? Oq : (z == 1 ? Ok : Ov);
  float scale = z == 0 ? 0.125f : 1.0f;
  int m0 = blockIdx.y * 128, n0 = blockIdx.x * 128;
  f32x4 acc[4][4] = {};
  gemm_core(A, W, m0, n0, As, Bs, acc);
  int t = threadIdx.x, l = t & 63, w = t >> 6;
  int wr = w >> 1, wc = w & 1, lr = l & 15, lg = l >> 4;
#pragma unroll
  for (int mi = 0; mi < 4; ++mi) {
#pragma unroll
    for (int ni = 0; ni < 4; ++ni) {
      int col = n0 + wc * 64 + ni * 16 + lr;
      float bb = bias[col];
      int row = m0 + wr * 64 + mi * 16 + lg * 4;
      bf16_t* op = O + (size_t)row * D_ + col;
#pragma unroll
      for (int r = 0; r < 4; ++r)
        op[(size_t)r * D_] = (bf16_t)((acc[mi][ni][r] + bb) * scale);
    }
  }
}

// ---------------- proj GEMM: out fp32 = acc + bo + x (residual) ----------------
__global__ __launch_bounds__(256) void gemm_proj(
    const bf16_t* __restrict__ A, const bf16_t* __restrict__ W,
    const float* __restrict__ bias, const float* __restrict__ xres,
    float* __restrict__ O) {
  __shared__ bf16_t As[128 * 32], Bs[128 * 32];
  int m0 = blockIdx.y * 128, n0 = blockIdx.x * 128;
  f32x4 acc[4][4] = {};
  gemm_core(A, W, m0, n0, As, Bs, acc);
  int t = threadIdx.x, l = t & 63, w = t >> 6;
  int wr = w >> 1, wc = w & 1, lr = l & 15, lg = l >> 4;
#pragma unroll
  for (int mi = 0; mi < 4; ++mi) {
#pragma unroll
    for (int ni = 0; ni < 4; ++ni) {
      int col = n0 + wc * 64 + ni * 16 + lr;
      float bb = bias[col];
      int row = m0 + wr * 64 + mi * 16 + lg * 4;
#pragma unroll
      for (int r = 0; r < 4; ++r) {
        size_t idx = (size_t)(row + r) * D_ + col;
        O[idx] = acc[mi][ni][r] + bb + xres[idx];
      }
    }
  }
}

// ---------------- V transpose: [128][1024][64] -> [128][64][1024] ----------------
__global__ __launch_bounds__(256) void transpose_v(const bf16_t* __restrict__ V,
                                                   bf16_t* __restrict__ Vt) {
  int gid = blockIdx.x * 256 + threadIdx.x;
  int s8 = gid & 127;
  int dh = (gid >> 7) & 63;
  int bh = gid >> 13;
  const bf16_t* src = V + (size_t)bh * 65536 + (size_t)(s8 * 8) * 64 + dh;
  bf16x8 v;
#pragma unroll
  for (int j = 0; j < 8; ++j) v[j] = src[(size_t)j * 64];
  *(bf16x8*)(Vt + (size_t)bh * 65536 + (size_t)dh * 1024 + s8 * 8) = v;
}

// ---------------- fused attention per (bh, 32-row q tile) ----------------
// exp(S) goes straight to LDS as bf16 during QK^T (no score registers, no
// spill); row-sums in 8 regs. 68 KB LDS -> 2 blocks/CU. Q pre-scaled.
#define SP_STRIDE 1064   // elems; 2128 B = 16B-aligned rows, bank-uniform
__global__ __launch_bounds__(512, 2) void attn_kernel(
    const bf16_t* __restrict__ Q, const bf16_t* __restrict__ K,
    const bf16_t* __restrict__ Vt, float* __restrict__ alpha,
    bf16_t* __restrict__ ctx) {
  __shared__ bf16_t sP[32][SP_STRIDE];
  __shared__ float sRS[8][32];
  __shared__ float sL[32];

  int id = blockIdx.x;
  // same XCD sweeps 32 consecutive q-tiles of one head (K/V stay L2-hot)
  int g = id >> 3, x = id & 7;
  int qt = g & 31;
  int bh = ((g >> 5) << 3) | x;
  int q0 = qt * 32;

  const bf16_t* Qb = Q + (size_t)bh * 65536;
  const bf16_t* Kb = K + (size_t)bh * 65536;
  const bf16_t* Vb = Vt + (size_t)bh * 65536;
  float* Ab = alpha + (size_t)bh * 1048576 + (size_t)q0 * 1024;

  int t = threadIdx.x, l = t & 63, w = t >> 6;
  int lr = l & 15, lg = l >> 4;

  // Q fragments (rows q0+mi*16+lr, k-chunks kk*32+lg*8)
  bf16x8 qa[2][2];
#pragma unroll
  for (int mi = 0; mi < 2; ++mi)
#pragma unroll
    for (int kk = 0; kk < 2; ++kk)
      qa[mi][kk] = *(const bf16x8*)(Qb + (size_t)(q0 + mi * 16 + lr) * 64 + kk * 32 + lg * 8);

  // ---- Phase A: QK^T -> exp -> sP(bf16) + rowsum partials in regs ----
  f32x4 pa0 = {0.f, 0.f, 0.f, 0.f}, pa1 = {0.f, 0.f, 0.f, 0.f};
#pragma unroll
  for (int tt = 0; tt < 8; ++tt) {
    int n0 = w * 128 + tt * 16;
    bf16x8 kb0 = *(const bf16x8*)(Kb + (size_t)(n0 + lr) * 64 + lg * 8);
    bf16x8 kb1 = *(const bf16x8*)(Kb + (size_t)(n0 + lr) * 64 + 32 + lg * 8);
    f32x4 a0 = {0.f, 0.f, 0.f, 0.f};
    f32x4 a1 = {0.f, 0.f, 0.f, 0.f};
    a0 = mfma16(qa[0][0], kb0, a0);
    a0 = mfma16(qa[0][1], kb1, a0);
    a1 = mfma16(qa[1][0], kb0, a1);
    a1 = mfma16(qa[1][1], kb1, a1);
#pragma unroll
    for (int r = 0; r < 4; ++r) {
      float e0 = __expf(a0[r]);
      float e1 = __expf(a1[r]);
      pa0[r] += e0; pa1[r] += e1;
      sP[lg * 4 + r][n0 + lr] = (bf16_t)e0;
      sP[16 + lg * 4 + r][n0 + lr] = (bf16_t)e1;
    }
  }
  // reduce across the 16 lanes of each lg-group
#pragma unroll
  for (int off = 1; off <= 8; off <<= 1) {
#pragma unroll
    for (int r = 0; r < 4; ++r) {
      pa0[r] += __shfl_xor(pa0[r], off);
      pa1[r] += __shfl_xor(pa1[r], off);
    }
  }
  if (lr == 0) {
#pragma unroll
    for (int r = 0; r < 4; ++r) {
      sRS[w][lg * 4 + r] = pa0[r];
      sRS[w][16 + lg * 4 + r] = pa1[r];
    }
  }
  __syncthreads();
  if (t < 32) {
    float s = 0.f;
#pragma unroll
    for (int ww = 0; ww < 8; ++ww) s += sRS[ww][t];
    sL[t] = 1.0f / s;
  }
  __syncthreads();

  // ---- Phase B: alpha = sP * 1/L, fp32, fully coalesced (1 KB/wave-instr) ----
  {
    int c4 = t & 255, r0 = t >> 8;
#pragma unroll 4
    for (int j = 0; j < 16; ++j) {
      int row = j * 2 + r0;
      float inv = sL[row];
      bf16x4 p = *(const bf16x4*)&sP[row][c4 * 4];
      f32x4 o;
      o[0] = (float)p[0] * inv;
      o[1] = (float)p[1] * inv;
      o[2] = (float)p[2] * inv;
      o[3] = (float)p[3] * inv;
      *(f32x4*)(Ab + (size_t)row * 1024 + c4 * 4) = o;
    }
  }

  // ---- Phase C: PV from sP (bf16) x Vt(global); wave tile 16q x 16dh ----
  {
    int wm = w >> 2, wn = w & 3;
    f32x4 acc = {0.f, 0.f, 0.f, 0.f};
    const bf16_t* vp = Vb + (size_t)(wn * 16 + lr) * 1024 + lg * 8;
    const bf16_t* pp = &sP[wm * 16 + lr][lg * 8];
#pragma unroll 8
    for (int n0 = 0; n0 < 1024; n0 += 32) {
      bf16x8 ea = *(const bf16x8*)(pp + n0);
      bf16x8 vb = *(const bf16x8*)(vp + n0);
      acc = mfma16(ea, vb, acc);
    }
    bf16_t* cp = ctx + (size_t)bh * 65536 + (size_t)(q0 + wm * 16 + lg * 4) * 64 + wn * 16 + lr;
#pragma unroll
    for (int r = 0; r < 4; ++r)
      cp[(size_t)r * 64] = (bf16_t)(acc[r] * sL[wm * 16 + lg * 4 + r]);
  }
}

// ---------------- LayerNorm in place on d_out rows ----------------
__global__ __launch_bounds__(256) void ln_kernel(float* __restrict__ io,
                                                 const float* __restrict__ gamma,
                                                 const float* __restrict__ beta) {
  int row = blockIdx.x;
  int t = threadIdx.x;
  float* p = io + (size_t)row * 1024;
  f32x4 v = *(const f32x4*)(p + t * 4);
  float s = v[0] + v[1] + v[2] + v[3];
  float s2 = v[0] * v[0] + v[1] * v[1] + v[2] * v[2] + v[3] * v[3];
#pragma unroll
  for (int off = 1; off <= 32; off <<= 1) {
    s += __shfl_xor(s, off);
    s2 += __shfl_xor(s2, off);
  }
  __shared__ float ps[4], ps2[4];
  int w = t >> 6, l = t & 63;
  if (l == 0) { ps[w] = s; ps2[w] = s2; }
  __syncthreads();
  float S = ps[0] + ps[1] + ps[2] + ps[3];
  float S2 = ps2[0] + ps2[1] + ps2[2] + ps2[3];
  float mu = S * (1.f / 1024.f);
  float var = S2 * (1.f / 1024.f) - mu * mu;
  float rs = rsqrtf(var + 1e-5f);
  f32x4 g = *(const f32x4*)(gamma + t * 4);
  f32x4 b = *(const f32x4*)(beta + t * 4);
  f32x4 o;
  o[0] = (v[0] - mu) * rs * g[0] + b[0];
  o[1] = (v[1] - mu) * rs * g[1] + b[1];
  o[2] = (v[2] - mu) * rs * g[2] + b[2];
  o[3] = (v[3] - mu) * rs * g[3] + b[3];
  *(f32x4*)(p + t * 4) = o;
}

extern "C" void kernel_launch(void* const* d_in, const int* in_sizes, int n_in,
                              void* d_out, int out_size, void* d_ws, size_t ws_size,
                              hipStream_t stream) {
  const float* x = (const float*)d_in[0];
  const float* Wq = (const float*)d_in[1];
  const float* bq = (const float*)d_in[2];
  const float* Wk = (const float*)d_in[3];
  const float* bk = (const float*)d_in[4];
  const float* Wv = (const float*)d_in[5];
  const float* bv = (const float*)d_in[6];
  const float* Wo = (const float*)d_in[7];
  const float* bo = (const float*)d_in[8];
  const float* gamma = (const float*)d_in[9];
  const float* beta = (const float*)d_in[10];

  char* ws = (char*)d_ws;
  size_t off = 0;
  bf16_t* xb = (bf16_t*)(ws + off);  off += (size_t)M_ * D_ * 2;
  bf16_t* Wqb = (bf16_t*)(ws + off); off += (size_t)D_ * D_ * 2;
  bf16_t* Wkb = (bf16_t*)(ws + off); off += (size_t)D_ * D_ * 2;
  bf16_t* Wvb = (bf16_t*)(ws + off); off += (size_t)D_ * D_ * 2;
  bf16_t* Wob = (bf16_t*)(ws + off); off += (size_t)D_ * D_ * 2;
  bf16_t* Qb = (bf16_t*)(ws + off);  off += (size_t)M_ * D_ * 2;
  bf16_t* Kb = (bf16_t*)(ws + off);  off += (size_t)M_ * D_ * 2;
  bf16_t* Vb = (bf16_t*)(ws + off);  off += (size_t)M_ * D_ * 2;
  bf16_t* Vtb = (bf16_t*)(ws + off); off += (size_t)M_ * D_ * 2;
  bf16_t* ctxb = (bf16_t*)(ws + off); off += (size_t)M_ * D_ * 2;

  float* out0 = (float*)d_out;
  float* alpha = out0 + (size_t)M_ * D_;

  cvt_bf16<<<4096, 256, 0, stream>>>(x, xb, 1048576);
  cvt_w4<<<2048, 256, 0, stream>>>(Wq, Wk, Wv, Wo, Wqb, Wkb, Wvb, Wob);

  gemm_qkv<<<dim3(8, 64, 3), 256, 0, stream>>>(xb, Wqb, Wkb, Wvb, bq, bk, bv, Qb, Kb, Vb);
  transpose_v<<<4096, 256, 0, stream>>>(Vb, Vtb);
  attn_kernel<<<4096, 512, 0, stream>>>(Qb, Kb, Vtb, alpha, ctxb);
  gemm_proj<<<dim3(8, 64), 256, 0, stream>>>(ctxb, Wob, bo, x, out0);
  ln_kernel<<<8192, 256, 0, stream>>>(out0, gamma, beta);
}

// Round 4
// 401.201 us; speedup vs baseline: 1.1702x; 1.0693x over previous
//
#include <hip/hip_runtime.h>
#include <stdint.h>
#include <math.h>

typedef __bf16 bf16_t;
typedef float f32x4 __attribute__((ext_vector_type(4)));
typedef __bf16 bf16x8 __attribute__((ext_vector_type(8)));
typedef __bf16 bf16x4 __attribute__((ext_vector_type(4)));

#define D_ 1024
#define M_ 8192

__device__ __forceinline__ f32x4 mfma16(bf16x8 a, bf16x8 b, f32x4 c) {
  return __builtin_amdgcn_mfma_f32_16x16x32_bf16(a, b, c, 0, 0, 0);
}

__device__ __forceinline__ void gl_lds16(const bf16_t* g, bf16_t* l) {
  __builtin_amdgcn_global_load_lds(
      (const __attribute__((address_space(1))) unsigned int*)g,
      (__attribute__((address_space(3))) unsigned int*)l, 16, 0, 0);
}

// ---------------- all fp32 -> bf16 converts in ONE launch ----------------
// blocks [0,4096): x (1,048,576 groups of 8). blocks [4096,6144): 4 weights.
__global__ __launch_bounds__(256) void cvt_all(
    const float* __restrict__ x,
    const float* __restrict__ w0, const float* __restrict__ w1,
    const float* __restrict__ w2, const float* __restrict__ w3,
    bf16_t* __restrict__ xb,
    bf16_t* __restrict__ d0, bf16_t* __restrict__ d1,
    bf16_t* __restrict__ d2, bf16_t* __restrict__ d3) {
  int b = blockIdx.x;
  const float* s;
  bf16_t* d;
  int i;
  if (b < 4096) {
    s = x; d = xb; i = b * 256 + threadIdx.x;
  } else {
    int g = b - 4096;
    int which = g >> 9;
    s = which == 0 ? w0 : which == 1 ? w1 : which == 2 ? w2 : w3;
    d = which == 0 ? d0 : which == 1 ? d1 : which == 2 ? d2 : d3;
    i = (g & 511) * 256 + threadIdx.x;
  }
  const f32x4* p = (const f32x4*)(s + (size_t)i * 8);
  f32x4 a = p[0], bb = p[1];
  bf16x8 o;
  o[0] = (bf16_t)a.x; o[1] = (bf16_t)a.y; o[2] = (bf16_t)a.z; o[3] = (bf16_t)a.w;
  o[4] = (bf16_t)bb.x; o[5] = (bf16_t)bb.y; o[6] = (bf16_t)bb.z; o[7] = (bf16_t)bb.w;
  *(bf16x8*)(d + (size_t)i * 8) = o;
}

// ---------------- shared 128x128x(K=1024) bf16 GEMM core (C = A @ W^T) ----------------
__device__ __forceinline__ void gemm_core(const bf16_t* __restrict__ A,
                                          const bf16_t* __restrict__ W,
                                          int m0, int n0,
                                          bf16_t* As, bf16_t* Bs,
                                          f32x4 acc[4][4]) {
  const int t = threadIdx.x;
  const int l = t & 63, w = t >> 6;
  const int wr = w >> 1, wc = w & 1;
  const int lr = l & 15, lg = l >> 4;
  const int srow = t >> 2;
  const int scol = (t & 3) * 8;
  const bf16_t* gA0 = A + (size_t)(m0 + srow) * D_ + scol;
  const bf16_t* gA1 = A + (size_t)(m0 + 64 + srow) * D_ + scol;
  const bf16_t* gB0 = W + (size_t)(n0 + srow) * D_ + scol;
  const bf16_t* gB1 = W + (size_t)(n0 + 64 + srow) * D_ + scol;

  for (int k0 = 0; k0 < D_; k0 += 32) {
    gl_lds16(gA0 + k0, As + t * 8);
    gl_lds16(gA1 + k0, As + 2048 + t * 8);
    gl_lds16(gB0 + k0, Bs + t * 8);
    gl_lds16(gB1 + k0, Bs + 2048 + t * 8);
    __syncthreads();
    bf16x8 af[4], bfr[4];
#pragma unroll
    for (int i = 0; i < 4; ++i)
      af[i] = *(const bf16x8*)(As + (wr * 64 + i * 16 + lr) * 32 + lg * 8);
#pragma unroll
    for (int i = 0; i < 4; ++i)
      bfr[i] = *(const bf16x8*)(Bs + (wc * 64 + i * 16 + lr) * 32 + lg * 8);
#pragma unroll
    for (int mi = 0; mi < 4; ++mi)
#pragma unroll
      for (int ni = 0; ni < 4; ++ni)
        acc[mi][ni] = mfma16(af[mi], bfr[ni], acc[mi][ni]);
    __syncthreads();
  }
}

// ---------------- QKV GEMM: z selects (W, bias, out); out bf16 ----------------
// z==0 (Q): output pre-scaled by 0.125*log2(e) so attn can use exp2 directly.
__global__ __launch_bounds__(256) void gemm_qkv(
    const bf16_t* __restrict__ A,
    const bf16_t* __restrict__ Wq, const bf16_t* __restrict__ Wk, const bf16_t* __restrict__ Wv,
    const float* __restrict__ bq, const float* __restrict__ bk, const float* __restrict__ bv,
    bf16_t* __restrict__ Oq, bf16_t* __restrict__ Ok, bf16_t* __restrict__ Ov) {
  __shared__ bf16_t As[128 * 32], Bs[128 * 32];
  int z = blockIdx.z;
  const bf16_t* W = z == 0 ? Wq : (z == 1 ? Wk : Wv);
  const float* bias = z == 0 ? bq : (z == 1 ? bk : bv);
  bf16_t* O = z == 0 ? Oq : (z == 1 ? Ok : Ov);
  float scale = z == 0 ? 0.18033688f : 1.0f;  // 0.125 * log2(e)
  int m0 = blockIdx.y * 128, n0 = blockIdx.x * 128;
  f32x4 acc[4][4] = {};
  gemm_core(A, W, m0, n0, As, Bs, acc);
  int t = threadIdx.x, l = t & 63, w = t >> 6;
  int wr = w >> 1, wc = w & 1, lr = l & 15, lg = l >> 4;
#pragma unroll
  for (int mi = 0; mi < 4; ++mi) {
#pragma unroll
    for (int ni = 0; ni < 4; ++ni) {
      int col = n0 + wc * 64 + ni * 16 + lr;
      float bb = bias[col];
      int row = m0 + wr * 64 + mi * 16 + lg * 4;
      bf16_t* op = O + (size_t)row * D_ + col;
#pragma unroll
      for (int r = 0; r < 4; ++r)
        op[(size_t)r * D_] = (bf16_t)((acc[mi][ni][r] + bb) * scale);
    }
  }
}

// ---------------- proj GEMM: out fp32 = acc + bo + x (residual) ----------------
__global__ __launch_bounds__(256) void gemm_proj(
    const bf16_t* __restrict__ A, const bf16_t* __restrict__ W,
    const float* __restrict__ bias, const float* __restrict__ xres,
    float* __restrict__ O) {
  __shared__ bf16_t As[128 * 32], Bs[128 * 32];
  int m0 = blockIdx.y * 128, n0 = blockIdx.x * 128;
  f32x4 acc[4][4] = {};
  gemm_core(A, W, m0, n0, As, Bs, acc);
  int t = threadIdx.x, l = t & 63, w = t >> 6;
  int wr = w >> 1, wc = w & 1, lr = l & 15, lg = l >> 4;
#pragma unroll
  for (int mi = 0; mi < 4; ++mi) {
#pragma unroll
    for (int ni = 0; ni < 4; ++ni) {
      int col = n0 + wc * 64 + ni * 16 + lr;
      float bb = bias[col];
      int row = m0 + wr * 64 + mi * 16 + lg * 4;
#pragma unroll
      for (int r = 0; r < 4; ++r) {
        size_t idx = (size_t)(row + r) * D_ + col;
        O[idx] = acc[mi][ni][r] + bb + xres[idx];
      }
    }
  }
}

// ---------------- V transpose via LDS tile: [128][1024][64] -> [128][64][1024] ----------------
// Tile = 128 s x 64 dh. LDS rows padded to 33 dwords so the transposed
// column read is ~4-way worst (lane s-step = 8 rows * 33 dw = 264 ≡ 8 mod 32).
__global__ __launch_bounds__(256) void transpose_v(const bf16_t* __restrict__ V,
                                                   bf16_t* __restrict__ Vt) {
  __shared__ float sT[128 * 33];
  int bh = blockIdx.x >> 3, st = blockIdx.x & 7;
  int s0 = st * 128;
  int t = threadIdx.x;
  const bf16_t* src = V + (size_t)bh * 65536 + (size_t)s0 * 64;
  int li = t >> 3, lc = t & 7;
#pragma unroll
  for (int p = 0; p < 4; ++p) {
    int row = p * 32 + li;
    f32x4 v = *(const f32x4*)(src + (size_t)row * 64 + lc * 8);
    float* dst = &sT[row * 33 + lc * 4];
    dst[0] = v[0]; dst[1] = v[1]; dst[2] = v[2]; dst[3] = v[3];
  }
  __syncthreads();
  int sc = t & 15, dh0 = t >> 4;
  bf16_t* dstb = Vt + (size_t)bh * 65536;
#pragma unroll
  for (int p = 0; p < 4; ++p) {
    int dh = dh0 + p * 16;
    bf16x8 o;
#pragma unroll
    for (int j = 0; j < 8; ++j) {
      int s = sc * 8 + j;
      o[j] = ((const bf16_t*)&sT[s * 33 + (dh >> 1)])[dh & 1];
    }
    *(bf16x8*)(dstb + (size_t)dh * 1024 + s0 + sc * 8) = o;
  }
}

// ---------------- fused attention per (bh, 32-row q tile) ----------------
// exp2(S') straight to LDS as bf16 during QK^T; rowsums in regs.
// LDS 69 KB + <=128 VGPR (launch_bounds 512,4) -> 2 blocks/CU so the
// HBM-bound alpha-write phase overlaps other blocks' compute phases.
#define SP_STRIDE 1064
__global__ __launch_bounds__(512, 4) void attn_kernel(
    const bf16_t* __restrict__ Q, const bf16_t* __restrict__ K,
    const bf16_t* __restrict__ Vt, float* __restrict__ alpha,
    bf16_t* __restrict__ ctx) {
  __shared__ bf16_t sP[32][SP_STRIDE];
  __shared__ float sRS[8][32];
  __shared__ float sL[32];

  int id = blockIdx.x;
  int g = id >> 3, x = id & 7;
  int qt = g & 31;
  int bh = ((g >> 5) << 3) | x;
  int q0 = qt * 32;

  const bf16_t* Qb = Q + (size_t)bh * 65536;
  const bf16_t* Kb = K + (size_t)bh * 65536;
  const bf16_t* Vb = Vt + (size_t)bh * 65536;
  float* Ab = alpha + (size_t)bh * 1048576 + (size_t)q0 * 1024;

  int t = threadIdx.x, l = t & 63, w = t >> 6;
  int lr = l & 15, lg = l >> 4;

  bf16x8 qa[2][2];
#pragma unroll
  for (int mi = 0; mi < 2; ++mi)
#pragma unroll
    for (int kk = 0; kk < 2; ++kk)
      qa[mi][kk] = *(const bf16x8*)(Qb + (size_t)(q0 + mi * 16 + lr) * 64 + kk * 32 + lg * 8);

  // ---- Phase A: QK^T -> exp2 -> sP(bf16) + rowsum partials in regs ----
  f32x4 pa0 = {0.f, 0.f, 0.f, 0.f}, pa1 = {0.f, 0.f, 0.f, 0.f};
#pragma unroll
  for (int tt = 0; tt < 8; ++tt) {
    int n0 = w * 128 + tt * 16;
    bf16x8 kb0 = *(const bf16x8*)(Kb + (size_t)(n0 + lr) * 64 + lg * 8);
    bf16x8 kb1 = *(const bf16x8*)(Kb + (size_t)(n0 + lr) * 64 + 32 + lg * 8);
    f32x4 a0 = {0.f, 0.f, 0.f, 0.f};
    f32x4 a1 = {0.f, 0.f, 0.f, 0.f};
    a0 = mfma16(qa[0][0], kb0, a0);
    a0 = mfma16(qa[0][1], kb1, a0);
    a1 = mfma16(qa[1][0], kb0, a1);
    a1 = mfma16(qa[1][1], kb1, a1);
#pragma unroll
    for (int r = 0; r < 4; ++r) {
      float e0 = exp2f(a0[r]);
      float e1 = exp2f(a1[r]);
      pa0[r] += e0; pa1[r] += e1;
      sP[lg * 4 + r][n0 + lr] = (bf16_t)e0;
      sP[16 + lg * 4 + r][n0 + lr] = (bf16_t)e1;
    }
  }
#pragma unroll
  for (int off = 1; off <= 8; off <<= 1) {
#pragma unroll
    for (int r = 0; r < 4; ++r) {
      pa0[r] += __shfl_xor(pa0[r], off);
      pa1[r] += __shfl_xor(pa1[r], off);
    }
  }
  if (lr == 0) {
#pragma unroll
    for (int r = 0; r < 4; ++r) {
      sRS[w][lg * 4 + r] = pa0[r];
      sRS[w][16 + lg * 4 + r] = pa1[r];
    }
  }
  __syncthreads();
  if (t < 32) {
    float s = 0.f;
#pragma unroll
    for (int ww = 0; ww < 8; ++ww) s += sRS[ww][t];
    sL[t] = 1.0f / s;
  }
  __syncthreads();

  // ---- Phase B: alpha = sP * 1/L, fp32, coalesced ----
  {
    int c4 = t & 255, r0 = t >> 8;
#pragma unroll 4
    for (int j = 0; j < 16; ++j) {
      int row = j * 2 + r0;
      float inv = sL[row];
      bf16x4 p = *(const bf16x4*)&sP[row][c4 * 4];
      f32x4 o;
      o[0] = (float)p[0] * inv;
      o[1] = (float)p[1] * inv;
      o[2] = (float)p[2] * inv;
      o[3] = (float)p[3] * inv;
      *(f32x4*)(Ab + (size_t)row * 1024 + c4 * 4) = o;
    }
  }

  // ---- Phase C: PV from sP (bf16) x Vt(global); wave tile 16q x 16dh ----
  {
    int wm = w >> 2, wn = w & 3;
    f32x4 acc = {0.f, 0.f, 0.f, 0.f};
    const bf16_t* vp = Vb + (size_t)(wn * 16 + lr) * 1024 + lg * 8;
    const bf16_t* pp = &sP[wm * 16 + lr][lg * 8];
#pragma unroll 8
    for (int n0 = 0; n0 < 1024; n0 += 32) {
      bf16x8 ea = *(const bf16x8*)(pp + n0);
      bf16x8 vb = *(const bf16x8*)(vp + n0);
      acc = mfma16(ea, vb, acc);
    }
    bf16_t* cp = ctx + (size_t)bh * 65536 + (size_t)(q0 + wm * 16 + lg * 4) * 64 + wn * 16 + lr;
#pragma unroll
    for (int r = 0; r < 4; ++r)
      cp[(size_t)r * 64] = (bf16_t)(acc[r] * sL[wm * 16 + lg * 4 + r]);
  }
}

// ---------------- LayerNorm in place on d_out rows ----------------
__global__ __launch_bounds__(256) void ln_kernel(float* __restrict__ io,
                                                 const float* __restrict__ gamma,
                                                 const float* __restrict__ beta) {
  int row = blockIdx.x;
  int t = threadIdx.x;
  float* p = io + (size_t)row * 1024;
  f32x4 v = *(const f32x4*)(p + t * 4);
  float s = v[0] + v[1] + v[2] + v[3];
  float s2 = v[0] * v[0] + v[1] * v[1] + v[2] * v[2] + v[3] * v[3];
#pragma unroll
  for (int off = 1; off <= 32; off <<= 1) {
    s += __shfl_xor(s, off);
    s2 += __shfl_xor(s2, off);
  }
  __shared__ float ps[4], ps2[4];
  int w = t >> 6, l = t & 63;
  if (l == 0) { ps[w] = s; ps2[w] = s2; }
  __syncthreads();
  float S = ps[0] + ps[1] + ps[2] + ps[3];
  float S2 = ps2[0] + ps2[1] + ps2[2] + ps2[3];
  float mu = S * (1.f / 1024.f);
  float var = S2 * (1.f / 1024.f) - mu * mu;
  float rs = rsqrtf(var + 1e-5f);
  f32x4 g = *(const f32x4*)(gamma + t * 4);
  f32x4 b = *(const f32x4*)(beta + t * 4);
  f32x4 o;
  o[0] = (v[0] - mu) * rs * g[0] + b[0];
  o[1] = (v[1] - mu) * rs * g[1] + b[1];
  o[2] = (v[2] - mu) * rs * g[2] + b[2];
  o[3] = (v[3] - mu) * rs * g[3] + b[3];
  *(f32x4*)(p + t * 4) = o;
}

extern "C" void kernel_launch(void* const* d_in, const int* in_sizes, int n_in,
                              void* d_out, int out_size, void* d_ws, size_t ws_size,
                              hipStream_t stream) {
  const float* x = (const float*)d_in[0];
  const float* Wq = (const float*)d_in[1];
  const float* bq = (const float*)d_in[2];
  const float* Wk = (const float*)d_in[3];
  const float* bk = (const float*)d_in[4];
  const float* Wv = (const float*)d_in[5];
  const float* bv = (const float*)d_in[6];
  const float* Wo = (const float*)d_in[7];
  const float* bo = (const float*)d_in[8];
  const float* gamma = (const float*)d_in[9];
  const float* beta = (const float*)d_in[10];

  char* ws = (char*)d_ws;
  size_t off = 0;
  bf16_t* xb = (bf16_t*)(ws + off);  off += (size_t)M_ * D_ * 2;
  bf16_t* Wqb = (bf16_t*)(ws + off); off += (size_t)D_ * D_ * 2;
  bf16_t* Wkb = (bf16_t*)(ws + off); off += (size_t)D_ * D_ * 2;
  bf16_t* Wvb = (bf16_t*)(ws + off); off += (size_t)D_ * D_ * 2;
  bf16_t* Wob = (bf16_t*)(ws + off); off += (size_t)D_ * D_ * 2;
  bf16_t* Qb = (bf16_t*)(ws + off);  off += (size_t)M_ * D_ * 2;
  bf16_t* Kb = (bf16_t*)(ws + off);  off += (size_t)M_ * D_ * 2;
  bf16_t* Vb = (bf16_t*)(ws + off);  off += (size_t)M_ * D_ * 2;
  bf16_t* Vtb = (bf16_t*)(ws + off); off += (size_t)M_ * D_ * 2;
  bf16_t* ctxb = (bf16_t*)(ws + off); off += (size_t)M_ * D_ * 2;

  float* out0 = (float*)d_out;
  float* alpha = out0 + (size_t)M_ * D_;

  cvt_all<<<6144, 256, 0, stream>>>(x, Wq, Wk, Wv, Wo, xb, Wqb, Wkb, Wvb, Wob);

  gemm_qkv<<<dim3(8, 64, 3), 256, 0, stream>>>(xb, Wqb, Wkb, Wvb, bq, bk, bv, Qb, Kb, Vb);
  transpose_v<<<1024, 256, 0, stream>>>(Vb, Vtb);
  attn_kernel<<<4096, 512, 0, stream>>>(Qb, Kb, Vtb, alpha, ctxb);
  gemm_proj<<<dim3(8, 64), 256, 0, stream>>>(ctxb, Wob, bo, x, out0);
  ln_kernel<<<8192, 256, 0, stream>>>(out0, gamma, beta);
}

// Round 5
// 333.381 us; speedup vs baseline: 1.4083x; 1.2034x over previous
//
#include <hip/hip_runtime.h>
#include <stdint.h>
#include <math.h>

typedef __bf16 bf16_t;
typedef float f32x4 __attribute__((ext_vector_type(4)));
typedef float f32x2 __attribute__((ext_vector_type(2)));
typedef __bf16 bf16x8 __attribute__((ext_vector_type(8)));
typedef __bf16 bf16x4 __attribute__((ext_vector_type(4)));

#define D_ 1024
#define M_ 8192

__device__ __forceinline__ f32x4 mfma16(bf16x8 a, bf16x8 b, f32x4 c) {
  return __builtin_amdgcn_mfma_f32_16x16x32_bf16(a, b, c, 0, 0, 0);
}

__device__ __forceinline__ void gl_lds16(const bf16_t* g, bf16_t* l) {
  __builtin_amdgcn_global_load_lds(
      (const __attribute__((address_space(1))) unsigned int*)g,
      (__attribute__((address_space(3))) unsigned int*)l, 16, 0, 0);
}

// ---------------- all fp32 -> bf16 converts in ONE launch ----------------
__global__ __launch_bounds__(256) void cvt_all(
    const float* __restrict__ x,
    const float* __restrict__ w0, const float* __restrict__ w1,
    const float* __restrict__ w2, const float* __restrict__ w3,
    bf16_t* __restrict__ xb,
    bf16_t* __restrict__ d0, bf16_t* __restrict__ d1,
    bf16_t* __restrict__ d2, bf16_t* __restrict__ d3) {
  int b = blockIdx.x;
  const float* s;
  bf16_t* d;
  int i;
  if (b < 4096) {
    s = x; d = xb; i = b * 256 + threadIdx.x;
  } else {
    int g = b - 4096;
    int which = g >> 9;
    s = which == 0 ? w0 : which == 1 ? w1 : which == 2 ? w2 : w3;
    d = which == 0 ? d0 : which == 1 ? d1 : which == 2 ? d2 : d3;
    i = (g & 511) * 256 + threadIdx.x;
  }
  const f32x4* p = (const f32x4*)(s + (size_t)i * 8);
  f32x4 a = p[0], bb = p[1];
  bf16x8 o;
  o[0] = (bf16_t)a.x; o[1] = (bf16_t)a.y; o[2] = (bf16_t)a.z; o[3] = (bf16_t)a.w;
  o[4] = (bf16_t)bb.x; o[5] = (bf16_t)bb.y; o[6] = (bf16_t)bb.z; o[7] = (bf16_t)bb.w;
  *(bf16x8*)(d + (size_t)i * 8) = o;
}

// ---------------- shared 128x128x(K=1024) bf16 GEMM core (C = A @ W^T) ----------------
__device__ __forceinline__ void gemm_core(const bf16_t* __restrict__ A,
                                          const bf16_t* __restrict__ W,
                                          int m0, int n0,
                                          bf16_t* As, bf16_t* Bs,
                                          f32x4 acc[4][4]) {
  const int t = threadIdx.x;
  const int l = t & 63, w = t >> 6;
  const int wr = w >> 1, wc = w & 1;
  const int lr = l & 15, lg = l >> 4;
  const int srow = t >> 2;
  const int scol = (t & 3) * 8;
  const bf16_t* gA0 = A + (size_t)(m0 + srow) * D_ + scol;
  const bf16_t* gA1 = A + (size_t)(m0 + 64 + srow) * D_ + scol;
  const bf16_t* gB0 = W + (size_t)(n0 + srow) * D_ + scol;
  const bf16_t* gB1 = W + (size_t)(n0 + 64 + srow) * D_ + scol;

  for (int k0 = 0; k0 < D_; k0 += 32) {
    gl_lds16(gA0 + k0, As + t * 8);
    gl_lds16(gA1 + k0, As + 2048 + t * 8);
    gl_lds16(gB0 + k0, Bs + t * 8);
    gl_lds16(gB1 + k0, Bs + 2048 + t * 8);
    __syncthreads();
    bf16x8 af[4], bfr[4];
#pragma unroll
    for (int i = 0; i < 4; ++i)
      af[i] = *(const bf16x8*)(As + (wr * 64 + i * 16 + lr) * 32 + lg * 8);
#pragma unroll
    for (int i = 0; i < 4; ++i)
      bfr[i] = *(const bf16x8*)(Bs + (wc * 64 + i * 16 + lr) * 32 + lg * 8);
#pragma unroll
    for (int mi = 0; mi < 4; ++mi)
#pragma unroll
      for (int ni = 0; ni < 4; ++ni)
        acc[mi][ni] = mfma16(af[mi], bfr[ni], acc[mi][ni]);
    __syncthreads();
  }
}

// ---------------- QKV GEMM: z selects (W, bias, out); out bf16 ----------------
__global__ __launch_bounds__(256) void gemm_qkv(
    const bf16_t* __restrict__ A,
    const bf16_t* __restrict__ Wq, const bf16_t* __restrict__ Wk, const bf16_t* __restrict__ Wv,
    const float* __restrict__ bq, const float* __restrict__ bk, const float* __restrict__ bv,
    bf16_t* __restrict__ Oq, bf16_t* __restrict__ Ok, bf16_t* __restrict__ Ov) {
  __shared__ bf16_t As[128 * 32], Bs[128 * 32];
  int z = blockIdx.z;
  const bf16_t* W = z == 0 ? Wq : (z == 1 ? Wk : Wv);
  const float* bias = z == 0 ? bq : (z == 1 ? bk : bv);
  bf16_t* O = z == 0 ? Oq : (z == 1 ? Ok : Ov);
  float scale = z == 0 ? 0.18033688f : 1.0f;  // 0.125 * log2(e)
  int m0 = blockIdx.y * 128, n0 = blockIdx.x * 128;
  f32x4 acc[4][4] = {};
  gemm_core(A, W, m0, n0, As, Bs, acc);
  int t = threadIdx.x, l = t & 63, w = t >> 6;
  int wr = w >> 1, wc = w & 1, lr = l & 15, lg = l >> 4;
#pragma unroll
  for (int mi = 0; mi < 4; ++mi) {
#pragma unroll
    for (int ni = 0; ni < 4; ++ni) {
      int col = n0 + wc * 64 + ni * 16 + lr;
      float bb = bias[col];
      int row = m0 + wr * 64 + mi * 16 + lg * 4;
      bf16_t* op = O + (size_t)row * D_ + col;
#pragma unroll
      for (int r = 0; r < 4; ++r)
        op[(size_t)r * D_] = (bf16_t)((acc[mi][ni][r] + bb) * scale);
    }
  }
}

// ---------------- proj GEMM: out fp32 = acc + bo + x (residual) ----------------
__global__ __launch_bounds__(256) void gemm_proj(
    const bf16_t* __restrict__ A, const bf16_t* __restrict__ W,
    const float* __restrict__ bias, const float* __restrict__ xres,
    float* __restrict__ O) {
  __shared__ bf16_t As[128 * 32], Bs[128 * 32];
  int m0 = blockIdx.y * 128, n0 = blockIdx.x * 128;
  f32x4 acc[4][4] = {};
  gemm_core(A, W, m0, n0, As, Bs, acc);
  int t = threadIdx.x, l = t & 63, w = t >> 6;
  int wr = w >> 1, wc = w & 1, lr = l & 15, lg = l >> 4;
#pragma unroll
  for (int mi = 0; mi < 4; ++mi) {
#pragma unroll
    for (int ni = 0; ni < 4; ++ni) {
      int col = n0 + wc * 64 + ni * 16 + lr;
      float bb = bias[col];
      int row = m0 + wr * 64 + mi * 16 + lg * 4;
#pragma unroll
      for (int r = 0; r < 4; ++r) {
        size_t idx = (size_t)(row + r) * D_ + col;
        O[idx] = acc[mi][ni][r] + bb + xres[idx];
      }
    }
  }
}

// ---------------- V transpose via LDS tile ----------------
__global__ __launch_bounds__(256) void transpose_v(const bf16_t* __restrict__ V,
                                                   bf16_t* __restrict__ Vt) {
  __shared__ float sT[128 * 33];
  int bh = blockIdx.x >> 3, st = blockIdx.x & 7;
  int s0 = st * 128;
  int t = threadIdx.x;
  const bf16_t* src = V + (size_t)bh * 65536 + (size_t)s0 * 64;
  int li = t >> 3, lc = t & 7;
#pragma unroll
  for (int p = 0; p < 4; ++p) {
    int row = p * 32 + li;
    f32x4 v = *(const f32x4*)(src + (size_t)row * 64 + lc * 8);
    float* dst = &sT[row * 33 + lc * 4];
    dst[0] = v[0]; dst[1] = v[1]; dst[2] = v[2]; dst[3] = v[3];
  }
  __syncthreads();
  int sc = t & 15, dh0 = t >> 4;
  bf16_t* dstb = Vt + (size_t)bh * 65536;
#pragma unroll
  for (int p = 0; p < 4; ++p) {
    int dh = dh0 + p * 16;
    bf16x8 o;
#pragma unroll
    for (int j = 0; j < 8; ++j) {
      int s = sc * 8 + j;
      o[j] = ((const bf16_t*)&sT[s * 33 + (dh >> 1)])[dh & 1];
    }
    *(bf16x8*)(dstb + (size_t)dh * 1024 + s0 + sc * 8) = o;
  }
}

// ---------------- fused attention per (bh, 32-row q tile) ----------------
// Swapped QK^T: mfma(K,Q) -> lane holds 4 consecutive k for one q ->
// b64 LDS writes (2-way bank = free). Alpha write fused into PV loop
// (NT f32x4 stores hidden under MFMA). LDS ~69 KB, <=128 VGPR -> 2 blk/CU.
#define SP_STRIDE 1064
__global__ __launch_bounds__(512, 4) void attn_kernel(
    const bf16_t* __restrict__ Q, const bf16_t* __restrict__ K,
    const bf16_t* __restrict__ Vt, float* __restrict__ alpha,
    bf16_t* __restrict__ ctx) {
  __shared__ bf16_t sP[32][SP_STRIDE];
  __shared__ float sRS[8][32];
  __shared__ float sL[32];

  int id = blockIdx.x;
  int g = id >> 3, x = id & 7;
  int qt = g & 31;
  int bh = ((g >> 5) << 3) | x;
  int q0 = qt * 32;

  const bf16_t* Qb = Q + (size_t)bh * 65536;
  const bf16_t* Kb = K + (size_t)bh * 65536;
  const bf16_t* Vb = Vt + (size_t)bh * 65536;
  float* Ab = alpha + (size_t)bh * 1048576 + (size_t)q0 * 1024;

  int t = threadIdx.x, l = t & 63, w = t >> 6;
  int lr = l & 15, lg = l >> 4;

  // Q fragments (rows q0+mi*16+lr, dh-chunks kk*32+lg*8)
  bf16x8 qa[2][2];
#pragma unroll
  for (int mi = 0; mi < 2; ++mi)
#pragma unroll
    for (int kk = 0; kk < 2; ++kk)
      qa[mi][kk] = *(const bf16x8*)(Qb + (size_t)(q0 + mi * 16 + lr) * 64 + kk * 32 + lg * 8);

  // ---- Phase A: P^T = K @ Q^T -> exp2 -> sP (b64 writes), scalar rowsums ----
  float pa0 = 0.f, pa1 = 0.f;   // this lane's q = lr (half 0 / half 1)
#pragma unroll
  for (int tt = 0; tt < 8; ++tt) {
    int n0 = w * 128 + tt * 16;
    bf16x8 kb0 = *(const bf16x8*)(Kb + (size_t)(n0 + lr) * 64 + lg * 8);
    bf16x8 kb1 = *(const bf16x8*)(Kb + (size_t)(n0 + lr) * 64 + 32 + lg * 8);
    f32x4 a0 = {0.f, 0.f, 0.f, 0.f};
    f32x4 a1 = {0.f, 0.f, 0.f, 0.f};
    a0 = mfma16(kb0, qa[0][0], a0);
    a0 = mfma16(kb1, qa[0][1], a0);
    a1 = mfma16(kb0, qa[1][0], a1);
    a1 = mfma16(kb1, qa[1][1], a1);
    bf16x4 w0, w1;
#pragma unroll
    for (int r = 0; r < 4; ++r) {
      float e0 = exp2f(a0[r]);
      float e1 = exp2f(a1[r]);
      pa0 += e0; pa1 += e1;
      w0[r] = (bf16_t)e0;
      w1[r] = (bf16_t)e1;
    }
    *(bf16x4*)&sP[lr][n0 + lg * 4] = w0;
    *(bf16x4*)&sP[16 + lr][n0 + lg * 4] = w1;
  }
  // reduce across lg groups (lanes lr, lr+16, lr+32, lr+48)
  pa0 += __shfl_xor(pa0, 16); pa0 += __shfl_xor(pa0, 32);
  pa1 += __shfl_xor(pa1, 16); pa1 += __shfl_xor(pa1, 32);
  if (l < 16) {
    sRS[w][lr] = pa0;
    sRS[w][16 + lr] = pa1;
  }
  __syncthreads();
  if (t < 32) {
    float s = 0.f;
#pragma unroll
    for (int ww = 0; ww < 8; ++ww) s += sRS[ww][t];
    sL[t] = 1.0f / s;
  }
  __syncthreads();

  // ---- Phase B+C fused: PV MFMA loop with interleaved alpha NT stores ----
  {
    int wm = w >> 2, wn = w & 3;
    f32x4 acc = {0.f, 0.f, 0.f, 0.f};
    const bf16_t* vp = Vb + (size_t)(wn * 16 + lr) * 1024 + lg * 8;
    const bf16_t* pp = &sP[wm * 16 + lr][lg * 8];
    int arow = t >> 4, acol = (t & 15) * 4;
    float inv = sL[arow];
    const bf16_t* ap = &sP[arow][acol];
    float* aout = Ab + (size_t)arow * 1024 + acol;
#pragma unroll 4
    for (int n0 = 0; n0 < 1024; n0 += 64) {
      bf16x8 ea0 = *(const bf16x8*)(pp + n0);
      bf16x8 vb0 = *(const bf16x8*)(vp + n0);
      acc = mfma16(ea0, vb0, acc);
      bf16x8 ea1 = *(const bf16x8*)(pp + n0 + 32);
      bf16x8 vb1 = *(const bf16x8*)(vp + n0 + 32);
      acc = mfma16(ea1, vb1, acc);
      // alpha chunk: rows 0..31, cols n0..n0+64 (512 thr x f32x4)
      bf16x4 p = *(const bf16x4*)(ap + n0);
      f32x4 o;
      o[0] = (float)p[0] * inv;
      o[1] = (float)p[1] * inv;
      o[2] = (float)p[2] * inv;
      o[3] = (float)p[3] * inv;
      __builtin_nontemporal_store(o, (f32x4*)(aout + n0));
    }
    bf16_t* cp = ctx + (size_t)bh * 65536 + (size_t)(q0 + wm * 16 + lg * 4) * 64 + wn * 16 + lr;
#pragma unroll
    for (int r = 0; r < 4; ++r)
      cp[(size_t)r * 64] = (bf16_t)(acc[r] * sL[wm * 16 + lg * 4 + r]);
  }
}

// ---------------- LayerNorm in place on d_out rows ----------------
__global__ __launch_bounds__(256) void ln_kernel(float* __restrict__ io,
                                                 const float* __restrict__ gamma,
                                                 const float* __restrict__ beta) {
  int row = blockIdx.x;
  int t = threadIdx.x;
  float* p = io + (size_t)row * 1024;
  f32x4 v = *(const f32x4*)(p + t * 4);
  float s = v[0] + v[1] + v[2] + v[3];
  float s2 = v[0] * v[0] + v[1] * v[1] + v[2] * v[2] + v[3] * v[3];
#pragma unroll
  for (int off = 1; off <= 32; off <<= 1) {
    s += __shfl_xor(s, off);
    s2 += __shfl_xor(s2, off);
  }
  __shared__ float ps[4], ps2[4];
  int w = t >> 6, l = t & 63;
  if (l == 0) { ps[w] = s; ps2[w] = s2; }
  __syncthreads();
  float S = ps[0] + ps[1] + ps[2] + ps[3];
  float S2 = ps2[0] + ps2[1] + ps2[2] + ps2[3];
  float mu = S * (1.f / 1024.f);
  float var = S2 * (1.f / 1024.f) - mu * mu;
  float rs = rsqrtf(var + 1e-5f);
  f32x4 g = *(const f32x4*)(gamma + t * 4);
  f32x4 b = *(const f32x4*)(beta + t * 4);
  f32x4 o;
  o[0] = (v[0] - mu) * rs * g[0] + b[0];
  o[1] = (v[1] - mu) * rs * g[1] + b[1];
  o[2] = (v[2] - mu) * rs * g[2] + b[2];
  o[3] = (v[3] - mu) * rs * g[3] + b[3];
  *(f32x4*)(p + t * 4) = o;
}

extern "C" void kernel_launch(void* const* d_in, const int* in_sizes, int n_in,
                              void* d_out, int out_size, void* d_ws, size_t ws_size,
                              hipStream_t stream) {
  const float* x = (const float*)d_in[0];
  const float* Wq = (const float*)d_in[1];
  const float* bq = (const float*)d_in[2];
  const float* Wk = (const float*)d_in[3];
  const float* bk = (const float*)d_in[4];
  const float* Wv = (const float*)d_in[5];
  const float* bv = (const float*)d_in[6];
  const float* Wo = (const float*)d_in[7];
  const float* bo = (const float*)d_in[8];
  const float* gamma = (const float*)d_in[9];
  const float* beta = (const float*)d_in[10];

  char* ws = (char*)d_ws;
  size_t off = 0;
  bf16_t* xb = (bf16_t*)(ws + off);  off += (size_t)M_ * D_ * 2;
  bf16_t* Wqb = (bf16_t*)(ws + off); off += (size_t)D_ * D_ * 2;
  bf16_t* Wkb = (bf16_t*)(ws + off); off += (size_t)D_ * D_ * 2;
  bf16_t* Wvb = (bf16_t*)(ws + off); off += (size_t)D_ * D_ * 2;
  bf16_t* Wob = (bf16_t*)(ws + off); off += (size_t)D_ * D_ * 2;
  bf16_t* Qb = (bf16_t*)(ws + off);  off += (size_t)M_ * D_ * 2;
  bf16_t* Kb = (bf16_t*)(ws + off);  off += (size_t)M_ * D_ * 2;
  bf16_t* Vb = (bf16_t*)(ws + off);  off += (size_t)M_ * D_ * 2;
  bf16_t* Vtb = (bf16_t*)(ws + off); off += (size_t)M_ * D_ * 2;
  bf16_t* ctxb = (bf16_t*)(ws + off); off += (size_t)M_ * D_ * 2;

  float* out0 = (float*)d_out;
  float* alpha = out0 + (size_t)M_ * D_;

  cvt_all<<<6144, 256, 0, stream>>>(x, Wq, Wk, Wv, Wo, xb, Wqb, Wkb, Wvb, Wob);

  gemm_qkv<<<dim3(8, 64, 3), 256, 0, stream>>>(xb, Wqb, Wkb, Wvb, bq, bk, bv, Qb, Kb, Vb);
  transpose_v<<<1024, 256, 0, stream>>>(Vb, Vtb);
  attn_kernel<<<4096, 512, 0, stream>>>(Qb, Kb, Vtb, alpha, ctxb);
  gemm_proj<<<dim3(8, 64), 256, 0, stream>>>(ctxb, Wob, bo, x, out0);
  ln_kernel<<<8192, 256, 0, stream>>>(out0, gamma, beta);
}